// Round 2
// baseline (2540.528 us; speedup 1.0000x reference)
//
#include <hip/hip_runtime.h>

#define N_ 32
#define C_ 128
#define H_ 32
#define W_ 32
#define T_ 12
#define R_ 64
#define HW_ (H_*W_)           // 1024
#define HWT_ (HW_*T_)         // 12288
#define CHWT_ ((size_t)C_*HW_*T_)  // 1572864
#define NCHUNK_ 16            // hw chunks of 64 for stats

__device__ __forceinline__ float sigm(float v) {
    return 1.0f / (1.0f + __expf(-v));
}

// K1: fused stats — ONE pass over x producing both
//   ts_in[n,t,hw] = mean_c x[n,c,hw,t]
//   pooled_p[chunk,n,t,c] = sum_{hw in chunk} x[n,c,hw,t]   (k_lin sums chunks)
// block = (hw-chunk of 64, n), 256 threads = 4 waves; wave w owns c = w+4*ci.
// pooled reduction: xor32+xor16 pre-reduce, then 4-step reduce-scatter over the
// 16-lane group (slot = bitrev4(g)) -> 12 lanes each hold one t-sum -> ONE
// masked global store per c. 39 LDS-pipe ops/c vs 72 for the full butterfly.
__global__ __launch_bounds__(256) void k_stats(const float* __restrict__ x,
                                               float* __restrict__ ts_in,
                                               float* __restrict__ pooled_p) {
    int chunk = blockIdx.x;      // 0..15
    int n = blockIdx.y;
    int tid = threadIdx.x;
    int wave = tid >> 6;
    int lane = tid & 63;
    int hw = chunk * 64 + lane;

    __shared__ float ts_l[4][64 * T_];      // per-wave ts partials, 12 KB

    const float* xb = x + (size_t)n * CHWT_ + (size_t)hw * T_;

    float ts_acc[T_];
    #pragma unroll
    for (int j = 0; j < T_; ++j) ts_acc[j] = 0.f;

    int g = lane & 15;
    int up1 = g & 1, up2 = g & 2, up4 = g & 4, up8 = g & 8;
    int trev = ((g & 1) << 3) | ((g & 2) << 1) | ((g & 4) >> 1) | ((g & 8) >> 3);
    bool do_store = (lane < 16) && (trev < T_);
    float* pp = pooled_p + ((size_t)(chunk * N_ + n) * T_ + trev) * C_;

    #pragma unroll 2
    for (int ci = 0; ci < 32; ++ci) {
        int c = wave + 4 * ci;
        const float4* p = (const float4*)(xb + (size_t)c * HWT_);
        float4 v0 = p[0], v1 = p[1], v2 = p[2];
        float v[T_] = {v0.x, v0.y, v0.z, v0.w,
                       v1.x, v1.y, v1.z, v1.w,
                       v2.x, v2.y, v2.z, v2.w};
        #pragma unroll
        for (int j = 0; j < T_; ++j) ts_acc[j] += v[j];

        float wv[16];
        #pragma unroll
        for (int j = 0; j < T_; ++j) {
            float s = v[j];
            s += __shfl_xor(s, 32, 64);
            s += __shfl_xor(s, 16, 64);
            wv[j] = s;      // sum over lanes {l, l^16, l^32, l^48}
        }
        wv[12] = 0.f; wv[13] = 0.f; wv[14] = 0.f; wv[15] = 0.f;

        // reduce-scatter within 16-lane group: 8+4+2+1 exchanges
        #pragma unroll
        for (int i = 0; i < 8; ++i) {
            float send = up1 ? wv[i] : wv[i + 8];
            float recv = __shfl_xor(send, 1, 64);
            wv[i] = (up1 ? wv[i + 8] : wv[i]) + recv;
        }
        #pragma unroll
        for (int i = 0; i < 4; ++i) {
            float send = up2 ? wv[i] : wv[i + 4];
            float recv = __shfl_xor(send, 2, 64);
            wv[i] = (up2 ? wv[i + 4] : wv[i]) + recv;
        }
        #pragma unroll
        for (int i = 0; i < 2; ++i) {
            float send = up4 ? wv[i] : wv[i + 2];
            float recv = __shfl_xor(send, 4, 64);
            wv[i] = (up4 ? wv[i + 2] : wv[i]) + recv;
        }
        {
            float send = up8 ? wv[0] : wv[1];
            float recv = __shfl_xor(send, 8, 64);
            wv[0] = (up8 ? wv[1] : wv[0]) + recv;
        }
        if (do_store) pp[c] = wv[0];   // raw partial; k_lin scales by 1/1024
    }

    #pragma unroll
    for (int j = 0; j < T_; ++j) ts_l[wave][lane * T_ + j] = ts_acc[j];
    __syncthreads();

    for (int i = tid; i < 64 * T_; i += 256) {
        float s = ts_l[0][i] + ts_l[1][i] + ts_l[2][i] + ts_l[3][i];
        int hwl = i / T_;
        int t = i - hwl * T_;
        ts_in[(n * T_ + t) * HW_ + chunk * 64 + hwl] = s * (1.0f / 128.0f);
    }
}

// K2: merged conv + linears. grid (n, 37): part<32 -> conv row h=part;
// part==32 -> TC; part 33..36 -> SC quarter.
__global__ __launch_bounds__(256) void k_mid(const float* __restrict__ ts_in,
                                             const float* __restrict__ ts_w,
                                             const float* __restrict__ ts_b,
                                             const float* __restrict__ pooled_p,
                                             const float* __restrict__ tc_w,
                                             const float* __restrict__ tc_b,
                                             const float* __restrict__ sc_w,
                                             const float* __restrict__ sc_b,
                                             float* __restrict__ TS,
                                             float* __restrict__ TC,
                                             float* __restrict__ SC) {
    int n = blockIdx.x;
    int part = blockIdx.y;
    int tid = threadIdx.x;
    __shared__ __align__(16) float smem[9728];

    if (part < 32) {
        // ---- conv3x3 over T input channels -> R outputs, row h=part ----
        int h = part;
        float* rows = smem;            // [3][12][36] padded rows, 1296
        float* wl = smem + 1296;       // 6912 weights
        for (int i = tid; i < 3 * T_ * 36; i += 256) {
            int kh = i / (T_ * 36);
            int rem = i - kh * (T_ * 36);
            int t = rem / 36;
            int wp = rem - t * 36;
            int hr = h + kh - 1;
            float v = 0.f;
            if (wp >= 1 && wp <= 32 && hr >= 0 && hr < H_)
                v = ts_in[((n * T_ + t) * H_ + hr) * W_ + (wp - 1)];
            rows[i] = v;
        }
        for (int i = tid; i < R_ * 108; i += 256) wl[i] = ts_w[i];
        __syncthreads();
        int r = tid >> 2;
        int j = tid & 3;      // 8 consecutive output w at j*8
        float acc[8];
        float b = ts_b[r];
        #pragma unroll
        for (int wi = 0; wi < 8; ++wi) acc[wi] = b;
        for (int t = 0; t < T_; ++t) {
            #pragma unroll
            for (int kh = 0; kh < 3; ++kh) {
                const float* rp = rows + (kh * T_ + t) * 36 + j * 8;
                float4 ra = *(const float4*)rp;
                float4 rb = *(const float4*)(rp + 4);
                float2 rc = *(const float2*)(rp + 8);
                float win[10] = {ra.x, ra.y, ra.z, ra.w,
                                 rb.x, rb.y, rb.z, rb.w, rc.x, rc.y};
                const float* wt = wl + r * 108 + t * 9 + kh * 3;
                float w0 = wt[0], w1 = wt[1], w2 = wt[2];
                #pragma unroll
                for (int wi = 0; wi < 8; ++wi)
                    acc[wi] += win[wi] * w0 + win[wi + 1] * w1 + win[wi + 2] * w2;
            }
        }
        float* outp = TS + (size_t)(n * R_ + r) * HW_ + h * W_ + j * 8;
        float4 o0 = {sigm(acc[0]), sigm(acc[1]), sigm(acc[2]), sigm(acc[3])};
        float4 o1 = {sigm(acc[4]), sigm(acc[5]), sigm(acc[6]), sigm(acc[7])};
        *(float4*)outp = o0;
        *(float4*)(outp + 4) = o1;
    } else if (part == 32) {
        // ---- TC: (T,R) = sigmoid(pooled @ tc_w^T + b) ----
        float* pl = smem;              // [t][c] 1536
        float* twt = smem + 1536;      // [c][r] 8192
        for (int i = tid; i < T_ * C_; i += 256) {
            float s = 0.f;
            #pragma unroll
            for (int k = 0; k < NCHUNK_; ++k)
                s += pooled_p[((size_t)k * N_ + n) * (T_ * C_) + i];
            pl[i] = s * (1.0f / 1024.0f);
        }
        for (int i = tid; i < C_ * R_; i += 256) {
            int r = i >> 7;
            int c = i & 127;
            twt[c * R_ + r] = tc_w[i];
        }
        __syncthreads();
        for (int o = tid; o < T_ * R_; o += 256) {
            int t = o >> 6;
            int r = o & 63;
            float acc = tc_b[r];
            #pragma unroll 4
            for (int c = 0; c < C_; ++c) acc += pl[t * C_ + c] * twt[c * R_ + r];
            TC[n * T_ * R_ + o] = sigm(acc);
        }
    } else {
        // ---- SC quarter: c in [cq*32, cq*32+32) ----
        int c0 = (part - 33) * 32;
        float* pl = smem;              // [t][c] 1536
        float* sw = smem + 1536;       // [r][t] 768
        for (int i = tid; i < T_ * C_; i += 256) {
            float s = 0.f;
            #pragma unroll
            for (int k = 0; k < NCHUNK_; ++k)
                s += pooled_p[((size_t)k * N_ + n) * (T_ * C_) + i];
            pl[i] = s * (1.0f / 1024.0f);
        }
        for (int i = tid; i < R_ * T_; i += 256) sw[i] = sc_w[i];
        __syncthreads();
        for (int o = tid; o < 32 * R_; o += 256) {
            int c = c0 + (o >> 6);
            int r = o & 63;
            float acc = sc_b[r];
            #pragma unroll
            for (int t = 0; t < T_; ++t) acc += pl[t * C_ + c] * sw[r * T_ + t];
            SC[(size_t)n * C_ * R_ + c * R_ + r] = sigm(acc);
        }
    }
}

// K3: out[n,c,hw,t] = relu( (Σ_r TS·TC·SC) * x )
// block = (s-chunk of 32, n), 192 threads = 32 sl × 6 t-pairs.
// Thread owns 2 t-columns (w0[64], w1[64] in VGPRs; x/out dense float2).
// SC per c split: r=0..31 scalar path (32 SGPR -> double-bufferable),
// r=32..63 from LDS (8 ds_read_b128 broadcasts).
__global__ __launch_bounds__(192, 3) void k_main(const float* __restrict__ x,
                                                 const float* __restrict__ TS,
                                                 const float* __restrict__ TC,
                                                 const float* __restrict__ SC,
                                                 float* __restrict__ out) {
    int schunk = blockIdx.x;   // 0..31, 32 s each
    int n = blockIdx.y;
    int tid = threadIdx.x;
    __shared__ float tstl[R_ * 32];               // [r][sl] 8 KB
    __shared__ float tcl[T_ * R_];                // 3 KB
    __shared__ __align__(16) float sch[C_ * 32];  // SC upper half [c][r-32] 16 KB
    int s0 = schunk * 32;
    for (int i = tid; i < R_ * 32; i += 192) {
        int r = i >> 5;
        int sl = i & 31;
        tstl[i] = TS[(size_t)(n * R_ + r) * HW_ + s0 + sl];
    }
    for (int i = tid; i < T_ * R_; i += 192) tcl[i] = TC[n * T_ * R_ + i];
    const float* scb = SC + (size_t)n * C_ * R_;
    for (int i = tid; i < C_ * 32; i += 192) {
        int c = i >> 5;
        int k = i & 31;
        sch[i] = scb[c * R_ + 32 + k];
    }
    __syncthreads();
    int sl = tid / 6;          // 0..31
    int tp = tid - sl * 6;     // 0..5
    int t0 = tp * 2;
    float w0[R_], w1[R_];
    #pragma unroll
    for (int r = 0; r < R_; ++r) {
        float tv = tstl[r * 32 + sl];
        w0[r] = tcl[t0 * R_ + r] * tv;
        w1[r] = tcl[(t0 + 1) * R_ + r] * tv;
    }
    size_t base = (size_t)n * CHWT_ + (size_t)(s0 + sl) * T_ + t0;

    #pragma unroll 2
    for (int c = 0; c < C_; ++c) {
        float2 xg = *(const float2*)(x + base + (size_t)c * HWT_);
        const float4* spl = (const float4*)(scb + c * R_);        // r 0..31, scalar
        const float4* sph = (const float4*)(sch + c * 32);        // r 32..63, LDS
        float a0 = 0.f, a1 = 0.f, b0 = 0.f, b1 = 0.f;
        #pragma unroll
        for (int q = 0; q < 8; ++q) {
            float4 v = spl[q];
            a0 = fmaf(v.x, w0[4 * q + 0], a0);
            a1 = fmaf(v.y, w0[4 * q + 1], a1);
            a0 = fmaf(v.z, w0[4 * q + 2], a0);
            a1 = fmaf(v.w, w0[4 * q + 3], a1);
            b0 = fmaf(v.x, w1[4 * q + 0], b0);
            b1 = fmaf(v.y, w1[4 * q + 1], b1);
            b0 = fmaf(v.z, w1[4 * q + 2], b0);
            b1 = fmaf(v.w, w1[4 * q + 3], b1);
        }
        #pragma unroll
        for (int q = 0; q < 8; ++q) {
            float4 v = sph[q];
            a0 = fmaf(v.x, w0[32 + 4 * q + 0], a0);
            a1 = fmaf(v.y, w0[32 + 4 * q + 1], a1);
            a0 = fmaf(v.z, w0[32 + 4 * q + 2], a0);
            a1 = fmaf(v.w, w0[32 + 4 * q + 3], a1);
            b0 = fmaf(v.x, w1[32 + 4 * q + 0], b0);
            b1 = fmaf(v.y, w1[32 + 4 * q + 1], b1);
            b0 = fmaf(v.z, w1[32 + 4 * q + 2], b0);
            b1 = fmaf(v.w, w1[32 + 4 * q + 3], b1);
        }
        float r0 = (a0 + a1) * xg.x;
        float r1 = (b0 + b1) * xg.y;
        float2 o;
        o.x = r0 > 0.f ? r0 : 0.f;
        o.y = r1 > 0.f ? r1 : 0.f;
        *(float2*)(out + base + (size_t)c * HWT_) = o;
    }
}

extern "C" void kernel_launch(void* const* d_in, const int* in_sizes, int n_in,
                              void* d_out, int out_size, void* d_ws, size_t ws_size,
                              hipStream_t stream) {
    const float* x    = (const float*)d_in[0];
    const float* ts_w = (const float*)d_in[1];
    const float* ts_b = (const float*)d_in[2];
    const float* tc_w = (const float*)d_in[3];
    const float* tc_b = (const float*)d_in[4];
    const float* sc_w = (const float*)d_in[5];
    const float* sc_b = (const float*)d_in[6];
    float* out = (float*)d_out;

    float* ws       = (float*)d_ws;
    float* ts_in    = ws;                          // 393216 floats
    float* pooled_p = ts_in + 393216;              // 786432
    float* TS       = pooled_p + 786432;           // 2097152
    float* TC       = TS + 2097152;                // 24576
    float* SC       = TC + 24576;                  // 262144   (~14.3 MB)

    hipLaunchKernelGGL(k_stats, dim3(NCHUNK_, 32), dim3(256), 0, stream, x, ts_in, pooled_p);
    hipLaunchKernelGGL(k_mid, dim3(32, 37), dim3(256), 0, stream,
                       ts_in, ts_w, ts_b, pooled_p, tc_w, tc_b, sc_w, sc_b, TS, TC, SC);
    hipLaunchKernelGGL(k_main, dim3(32, 32), dim3(192), 0, stream, x, TS, TC, SC, out);
}

// Round 3
// 800.137 us; speedup vs baseline: 3.1751x; 3.1751x over previous
//
#include <hip/hip_runtime.h>

#define N_ 32
#define C_ 128
#define H_ 32
#define W_ 32
#define T_ 12
#define R_ 64
#define HW_ (H_*W_)           // 1024
#define HWT_ (HW_*T_)         // 12288
#define CHWT_ ((size_t)C_*HW_*T_)  // 1572864
#define NCHUNK_ 16            // hw chunks of 64 for stats

__device__ __forceinline__ float sigm(float v) {
    return 1.0f / (1.0f + __expf(-v));
}

// K1: fused stats — ONE pass over x producing both
//   ts_in[n,t,hw] = mean_c x[n,c,hw,t]
//   pooled_p[chunk,n,t,c] = sum_{hw in chunk} x[n,c,hw,t]   (k_mid sums chunks)
__global__ __launch_bounds__(256) void k_stats(const float* __restrict__ x,
                                               float* __restrict__ ts_in,
                                               float* __restrict__ pooled_p) {
    int chunk = blockIdx.x;      // 0..15
    int n = blockIdx.y;
    int tid = threadIdx.x;
    int wave = tid >> 6;
    int lane = tid & 63;
    int hw = chunk * 64 + lane;

    __shared__ float ts_l[4][64 * T_];      // per-wave ts partials, 12 KB

    const float* xb = x + (size_t)n * CHWT_ + (size_t)hw * T_;

    float ts_acc[T_];
    #pragma unroll
    for (int j = 0; j < T_; ++j) ts_acc[j] = 0.f;

    int g = lane & 15;
    int up1 = g & 1, up2 = g & 2, up4 = g & 4, up8 = g & 8;
    int trev = ((g & 1) << 3) | ((g & 2) << 1) | ((g & 4) >> 1) | ((g & 8) >> 3);
    bool do_store = (lane < 16) && (trev < T_);
    float* pp = pooled_p + ((size_t)(chunk * N_ + n) * T_ + trev) * C_;

    #pragma unroll 2
    for (int ci = 0; ci < 32; ++ci) {
        int c = wave + 4 * ci;
        const float4* p = (const float4*)(xb + (size_t)c * HWT_);
        float4 v0 = p[0], v1 = p[1], v2 = p[2];
        float v[T_] = {v0.x, v0.y, v0.z, v0.w,
                       v1.x, v1.y, v1.z, v1.w,
                       v2.x, v2.y, v2.z, v2.w};
        #pragma unroll
        for (int j = 0; j < T_; ++j) ts_acc[j] += v[j];

        float wv[16];
        #pragma unroll
        for (int j = 0; j < T_; ++j) {
            float s = v[j];
            s += __shfl_xor(s, 32, 64);
            s += __shfl_xor(s, 16, 64);
            wv[j] = s;      // sum over lanes {l, l^16, l^32, l^48}
        }
        wv[12] = 0.f; wv[13] = 0.f; wv[14] = 0.f; wv[15] = 0.f;

        #pragma unroll
        for (int i = 0; i < 8; ++i) {
            float send = up1 ? wv[i] : wv[i + 8];
            float recv = __shfl_xor(send, 1, 64);
            wv[i] = (up1 ? wv[i + 8] : wv[i]) + recv;
        }
        #pragma unroll
        for (int i = 0; i < 4; ++i) {
            float send = up2 ? wv[i] : wv[i + 4];
            float recv = __shfl_xor(send, 2, 64);
            wv[i] = (up2 ? wv[i + 4] : wv[i]) + recv;
        }
        #pragma unroll
        for (int i = 0; i < 2; ++i) {
            float send = up4 ? wv[i] : wv[i + 2];
            float recv = __shfl_xor(send, 4, 64);
            wv[i] = (up4 ? wv[i + 2] : wv[i]) + recv;
        }
        {
            float send = up8 ? wv[0] : wv[1];
            float recv = __shfl_xor(send, 8, 64);
            wv[0] = (up8 ? wv[1] : wv[0]) + recv;
        }
        if (do_store) pp[c] = wv[0];   // raw partial; k_mid scales by 1/1024
    }

    #pragma unroll
    for (int j = 0; j < T_; ++j) ts_l[wave][lane * T_ + j] = ts_acc[j];
    __syncthreads();

    for (int i = tid; i < 64 * T_; i += 256) {
        float s = ts_l[0][i] + ts_l[1][i] + ts_l[2][i] + ts_l[3][i];
        int hwl = i / T_;
        int t = i - hwl * T_;
        ts_in[(n * T_ + t) * HW_ + chunk * 64 + hwl] = s * (1.0f / 128.0f);
    }
}

// K2: merged conv + linears. grid (n, 37): part<32 -> conv row h=part;
// part==32 -> TC; part 33..36 -> SC quarter.
__global__ __launch_bounds__(256) void k_mid(const float* __restrict__ ts_in,
                                             const float* __restrict__ ts_w,
                                             const float* __restrict__ ts_b,
                                             const float* __restrict__ pooled_p,
                                             const float* __restrict__ tc_w,
                                             const float* __restrict__ tc_b,
                                             const float* __restrict__ sc_w,
                                             const float* __restrict__ sc_b,
                                             float* __restrict__ TS,
                                             float* __restrict__ TC,
                                             float* __restrict__ SC) {
    int n = blockIdx.x;
    int part = blockIdx.y;
    int tid = threadIdx.x;
    __shared__ __align__(16) float smem[9728];

    if (part < 32) {
        int h = part;
        float* rows = smem;            // [3][12][36] padded rows, 1296
        float* wl = smem + 1296;       // 6912 weights
        for (int i = tid; i < 3 * T_ * 36; i += 256) {
            int kh = i / (T_ * 36);
            int rem = i - kh * (T_ * 36);
            int t = rem / 36;
            int wp = rem - t * 36;
            int hr = h + kh - 1;
            float v = 0.f;
            if (wp >= 1 && wp <= 32 && hr >= 0 && hr < H_)
                v = ts_in[((n * T_ + t) * H_ + hr) * W_ + (wp - 1)];
            rows[i] = v;
        }
        for (int i = tid; i < R_ * 108; i += 256) wl[i] = ts_w[i];
        __syncthreads();
        int r = tid >> 2;
        int j = tid & 3;      // 8 consecutive output w at j*8
        float acc[8];
        float b = ts_b[r];
        #pragma unroll
        for (int wi = 0; wi < 8; ++wi) acc[wi] = b;
        for (int t = 0; t < T_; ++t) {
            #pragma unroll
            for (int kh = 0; kh < 3; ++kh) {
                const float* rp = rows + (kh * T_ + t) * 36 + j * 8;
                float4 ra = *(const float4*)rp;
                float4 rb = *(const float4*)(rp + 4);
                float2 rc = *(const float2*)(rp + 8);
                float win[10] = {ra.x, ra.y, ra.z, ra.w,
                                 rb.x, rb.y, rb.z, rb.w, rc.x, rc.y};
                const float* wt = wl + r * 108 + t * 9 + kh * 3;
                float w0 = wt[0], w1 = wt[1], w2 = wt[2];
                #pragma unroll
                for (int wi = 0; wi < 8; ++wi)
                    acc[wi] += win[wi] * w0 + win[wi + 1] * w1 + win[wi + 2] * w2;
            }
        }
        float* outp = TS + (size_t)(n * R_ + r) * HW_ + h * W_ + j * 8;
        float4 o0 = {sigm(acc[0]), sigm(acc[1]), sigm(acc[2]), sigm(acc[3])};
        float4 o1 = {sigm(acc[4]), sigm(acc[5]), sigm(acc[6]), sigm(acc[7])};
        *(float4*)outp = o0;
        *(float4*)(outp + 4) = o1;
    } else if (part == 32) {
        float* pl = smem;              // [t][c] 1536
        float* twt = smem + 1536;      // [c][r] 8192
        for (int i = tid; i < T_ * C_; i += 256) {
            float s = 0.f;
            #pragma unroll
            for (int k = 0; k < NCHUNK_; ++k)
                s += pooled_p[((size_t)k * N_ + n) * (T_ * C_) + i];
            pl[i] = s * (1.0f / 1024.0f);
        }
        for (int i = tid; i < C_ * R_; i += 256) {
            int r = i >> 7;
            int c = i & 127;
            twt[c * R_ + r] = tc_w[i];
        }
        __syncthreads();
        for (int o = tid; o < T_ * R_; o += 256) {
            int t = o >> 6;
            int r = o & 63;
            float acc = tc_b[r];
            #pragma unroll 4
            for (int c = 0; c < C_; ++c) acc += pl[t * C_ + c] * twt[c * R_ + r];
            TC[n * T_ * R_ + o] = sigm(acc);
        }
    } else {
        int c0 = (part - 33) * 32;
        float* pl = smem;              // [t][c] 1536
        float* sw = smem + 1536;       // [r][t] 768
        for (int i = tid; i < T_ * C_; i += 256) {
            float s = 0.f;
            #pragma unroll
            for (int k = 0; k < NCHUNK_; ++k)
                s += pooled_p[((size_t)k * N_ + n) * (T_ * C_) + i];
            pl[i] = s * (1.0f / 1024.0f);
        }
        for (int i = tid; i < R_ * T_; i += 256) sw[i] = sc_w[i];
        __syncthreads();
        for (int o = tid; o < 32 * R_; o += 256) {
            int c = c0 + (o >> 6);
            int r = o & 63;
            float acc = sc_b[r];
            #pragma unroll
            for (int t = 0; t < T_; ++t) acc += pl[t * C_ + c] * sw[r * T_ + t];
            SC[(size_t)n * C_ * R_ + c * R_ + r] = sigm(acc);
        }
    }
}

// K3: out[n,c,s,t] = relu( (Σ_r TS[r,s]·TC[t,r]·SC[c,r]) * x[n,c,s,t] )
// block = 384 thr = 6 waves; wave = 32 (s,t) columns × 2 r-halves.
// lane l: j=l&31 -> stp = wv*32+j (s,t column), half=l>>5 -> r in [32h,32h+32).
// Per thread: w[32] only (no spill), 8 same-addr float4 SC loads per c,
// 32 FMAs; c processed in pairs; one shfl_xor(32) combines halves and gives
// every lane one output -> dense 128B store segments.
__global__ __launch_bounds__(384, 4) void k_main(const float* __restrict__ x,
                                                 const float* __restrict__ TS,
                                                 const float* __restrict__ TC,
                                                 const float* __restrict__ SC,
                                                 float* __restrict__ out) {
    int schunk = blockIdx.x;   // 0..63, 16 s each
    int n = blockIdx.y;
    int tid = threadIdx.x;
    __shared__ float tstl[R_ * 16];               // [r][sl] 4 KB
    __shared__ float tcl[T_ * R_];                // 3 KB
    int s0 = schunk * 16;
    for (int i = tid; i < R_ * 16; i += 384) {
        int r = i >> 4;
        int sl = i & 15;
        tstl[i] = TS[(size_t)(n * R_ + r) * HW_ + s0 + sl];
    }
    for (int i = tid; i < T_ * R_; i += 384) tcl[i] = TC[n * T_ * R_ + i];
    __syncthreads();

    int wv = tid >> 6;         // 0..5
    int l = tid & 63;
    int half = l >> 5;         // r-half
    int j = l & 31;
    int stp = wv * 32 + j;     // 0..191 = sl*12 + t
    int sl = stp / T_;
    int t = stp - sl * T_;

    float w[32];
    #pragma unroll
    for (int k = 0; k < 32; ++k) {
        int r = half * 32 + k;
        w[k] = tcl[t * R_ + r] * tstl[r * 16 + sl];
    }

    size_t base = (size_t)n * CHWT_ + (size_t)s0 * T_ + stp;
    const float* scb = SC + (size_t)n * C_ * R_;

    #pragma unroll 2
    for (int c0 = 0; c0 < C_; c0 += 2) {
        int cmy = c0 + half;                       // channel this lane outputs
        float xv = x[base + (size_t)cmy * HWT_];
        const float4* q0 = (const float4*)(scb + c0 * R_ + half * 32);
        const float4* q1 = (const float4*)(scb + (c0 + 1) * R_ + half * 32);
        float p0a = 0.f, p0b = 0.f, p1a = 0.f, p1b = 0.f;
        #pragma unroll
        for (int q = 0; q < 8; ++q) {
            float4 v0 = q0[q];
            float4 v1 = q1[q];
            p0a = fmaf(v0.x, w[4 * q + 0], p0a);
            p0b = fmaf(v0.y, w[4 * q + 1], p0b);
            p0a = fmaf(v0.z, w[4 * q + 2], p0a);
            p0b = fmaf(v0.w, w[4 * q + 3], p0b);
            p1a = fmaf(v1.x, w[4 * q + 0], p1a);
            p1b = fmaf(v1.y, w[4 * q + 1], p1b);
            p1a = fmaf(v1.z, w[4 * q + 2], p1a);
            p1b = fmaf(v1.w, w[4 * q + 3], p1b);
        }
        float p0 = p0a + p0b;          // my r-half partial of channel c0
        float p1 = p1a + p1b;          // my r-half partial of channel c0+1
        float keep = half ? p1 : p0;   // partial for MY output channel
        float send = half ? p0 : p1;   // partial the partner needs
        float recv = __shfl_xor(send, 32, 64);
        float full = keep + recv;
        float res = full * xv;
        out[base + (size_t)cmy * HWT_] = res > 0.f ? res : 0.f;
    }
}

extern "C" void kernel_launch(void* const* d_in, const int* in_sizes, int n_in,
                              void* d_out, int out_size, void* d_ws, size_t ws_size,
                              hipStream_t stream) {
    const float* x    = (const float*)d_in[0];
    const float* ts_w = (const float*)d_in[1];
    const float* ts_b = (const float*)d_in[2];
    const float* tc_w = (const float*)d_in[3];
    const float* tc_b = (const float*)d_in[4];
    const float* sc_w = (const float*)d_in[5];
    const float* sc_b = (const float*)d_in[6];
    float* out = (float*)d_out;

    float* ws       = (float*)d_ws;
    float* ts_in    = ws;                          // 393216 floats
    float* pooled_p = ts_in + 393216;              // 786432
    float* TS       = pooled_p + 786432;           // 2097152
    float* TC       = TS + 2097152;                // 24576
    float* SC       = TC + 24576;                  // 262144   (~14.3 MB)

    hipLaunchKernelGGL(k_stats, dim3(NCHUNK_, 32), dim3(256), 0, stream, x, ts_in, pooled_p);
    hipLaunchKernelGGL(k_mid, dim3(32, 37), dim3(256), 0, stream,
                       ts_in, ts_w, ts_b, pooled_p, tc_w, tc_b, sc_w, sc_b, TS, TC, SC);
    hipLaunchKernelGGL(k_main, dim3(64, 32), dim3(384), 0, stream, x, TS, TC, SC, out);
}

// Round 4
// 537.472 us; speedup vs baseline: 4.7268x; 1.4887x over previous
//
#include <hip/hip_runtime.h>

#define N_ 32
#define C_ 128
#define H_ 32
#define W_ 32
#define T_ 12
#define R_ 64
#define HW_ (H_*W_)           // 1024
#define HWT_ (HW_*T_)         // 12288
#define CHWT_ ((size_t)C_*HW_*T_)  // 1572864
#define NCHUNK_ 16            // hw chunks of 64 for stats

__device__ __forceinline__ float sigm(float v) {
    return 1.0f / (1.0f + __expf(-v));
}

// K1: fused stats — ONE pass over x producing both
//   ts_in[n,t,hw] = mean_c x[n,c,hw,t]
//   pooled_p[chunk,n,t,c] = sum_{hw in chunk} x[n,c,hw,t]   (k_mid sums chunks)
__global__ __launch_bounds__(256) void k_stats(const float* __restrict__ x,
                                               float* __restrict__ ts_in,
                                               float* __restrict__ pooled_p) {
    int chunk = blockIdx.x;      // 0..15
    int n = blockIdx.y;
    int tid = threadIdx.x;
    int wave = tid >> 6;
    int lane = tid & 63;
    int hw = chunk * 64 + lane;

    __shared__ float ts_l[4][64 * T_];      // per-wave ts partials, 12 KB

    const float* xb = x + (size_t)n * CHWT_ + (size_t)hw * T_;

    float ts_acc[T_];
    #pragma unroll
    for (int j = 0; j < T_; ++j) ts_acc[j] = 0.f;

    int g = lane & 15;
    int up1 = g & 1, up2 = g & 2, up4 = g & 4, up8 = g & 8;
    int trev = ((g & 1) << 3) | ((g & 2) << 1) | ((g & 4) >> 1) | ((g & 8) >> 3);
    bool do_store = (lane < 16) && (trev < T_);
    float* pp = pooled_p + ((size_t)(chunk * N_ + n) * T_ + trev) * C_;

    #pragma unroll 2
    for (int ci = 0; ci < 32; ++ci) {
        int c = wave + 4 * ci;
        const float4* p = (const float4*)(xb + (size_t)c * HWT_);
        float4 v0 = p[0], v1 = p[1], v2 = p[2];
        float v[T_] = {v0.x, v0.y, v0.z, v0.w,
                       v1.x, v1.y, v1.z, v1.w,
                       v2.x, v2.y, v2.z, v2.w};
        #pragma unroll
        for (int j = 0; j < T_; ++j) ts_acc[j] += v[j];

        float wv[16];
        #pragma unroll
        for (int j = 0; j < T_; ++j) {
            float s = v[j];
            s += __shfl_xor(s, 32, 64);
            s += __shfl_xor(s, 16, 64);
            wv[j] = s;      // sum over lanes {l, l^16, l^32, l^48}
        }
        wv[12] = 0.f; wv[13] = 0.f; wv[14] = 0.f; wv[15] = 0.f;

        #pragma unroll
        for (int i = 0; i < 8; ++i) {
            float send = up1 ? wv[i] : wv[i + 8];
            float recv = __shfl_xor(send, 1, 64);
            wv[i] = (up1 ? wv[i + 8] : wv[i]) + recv;
        }
        #pragma unroll
        for (int i = 0; i < 4; ++i) {
            float send = up2 ? wv[i] : wv[i + 4];
            float recv = __shfl_xor(send, 2, 64);
            wv[i] = (up2 ? wv[i + 4] : wv[i]) + recv;
        }
        #pragma unroll
        for (int i = 0; i < 2; ++i) {
            float send = up4 ? wv[i] : wv[i + 2];
            float recv = __shfl_xor(send, 4, 64);
            wv[i] = (up4 ? wv[i + 2] : wv[i]) + recv;
        }
        {
            float send = up8 ? wv[0] : wv[1];
            float recv = __shfl_xor(send, 8, 64);
            wv[0] = (up8 ? wv[1] : wv[0]) + recv;
        }
        if (do_store) pp[c] = wv[0];   // raw partial; k_mid scales by 1/1024
    }

    #pragma unroll
    for (int j = 0; j < T_; ++j) ts_l[wave][lane * T_ + j] = ts_acc[j];
    __syncthreads();

    for (int i = tid; i < 64 * T_; i += 256) {
        float s = ts_l[0][i] + ts_l[1][i] + ts_l[2][i] + ts_l[3][i];
        int hwl = i / T_;
        int t = i - hwl * T_;
        ts_in[(n * T_ + t) * HW_ + chunk * 64 + hwl] = s * (1.0f / 128.0f);
    }
}

// K2: merged conv + linears. grid (n, 37): part<32 -> conv row h=part;
// part==32 -> TC; part 33..36 -> SC quarter.
__global__ __launch_bounds__(256) void k_mid(const float* __restrict__ ts_in,
                                             const float* __restrict__ ts_w,
                                             const float* __restrict__ ts_b,
                                             const float* __restrict__ pooled_p,
                                             const float* __restrict__ tc_w,
                                             const float* __restrict__ tc_b,
                                             const float* __restrict__ sc_w,
                                             const float* __restrict__ sc_b,
                                             float* __restrict__ TS,
                                             float* __restrict__ TC,
                                             float* __restrict__ SC) {
    int n = blockIdx.x;
    int part = blockIdx.y;
    int tid = threadIdx.x;
    __shared__ __align__(16) float smem[9728];

    if (part < 32) {
        int h = part;
        float* rows = smem;            // [3][12][36] padded rows, 1296
        float* wl = smem + 1296;       // 6912 weights
        for (int i = tid; i < 3 * T_ * 36; i += 256) {
            int kh = i / (T_ * 36);
            int rem = i - kh * (T_ * 36);
            int t = rem / 36;
            int wp = rem - t * 36;
            int hr = h + kh - 1;
            float v = 0.f;
            if (wp >= 1 && wp <= 32 && hr >= 0 && hr < H_)
                v = ts_in[((n * T_ + t) * H_ + hr) * W_ + (wp - 1)];
            rows[i] = v;
        }
        for (int i = tid; i < R_ * 108; i += 256) wl[i] = ts_w[i];
        __syncthreads();
        int r = tid >> 2;
        int j = tid & 3;      // 8 consecutive output w at j*8
        float acc[8];
        float b = ts_b[r];
        #pragma unroll
        for (int wi = 0; wi < 8; ++wi) acc[wi] = b;
        for (int t = 0; t < T_; ++t) {
            #pragma unroll
            for (int kh = 0; kh < 3; ++kh) {
                const float* rp = rows + (kh * T_ + t) * 36 + j * 8;
                float4 ra = *(const float4*)rp;
                float4 rb = *(const float4*)(rp + 4);
                float2 rc = *(const float2*)(rp + 8);
                float win[10] = {ra.x, ra.y, ra.z, ra.w,
                                 rb.x, rb.y, rb.z, rb.w, rc.x, rc.y};
                const float* wt = wl + r * 108 + t * 9 + kh * 3;
                float w0 = wt[0], w1 = wt[1], w2 = wt[2];
                #pragma unroll
                for (int wi = 0; wi < 8; ++wi)
                    acc[wi] += win[wi] * w0 + win[wi + 1] * w1 + win[wi + 2] * w2;
            }
        }
        float* outp = TS + (size_t)(n * R_ + r) * HW_ + h * W_ + j * 8;
        float4 o0 = {sigm(acc[0]), sigm(acc[1]), sigm(acc[2]), sigm(acc[3])};
        float4 o1 = {sigm(acc[4]), sigm(acc[5]), sigm(acc[6]), sigm(acc[7])};
        *(float4*)outp = o0;
        *(float4*)(outp + 4) = o1;
    } else if (part == 32) {
        float* pl = smem;              // [t][c] 1536
        float* twt = smem + 1536;      // [c][r] 8192
        for (int i = tid; i < T_ * C_; i += 256) {
            float s = 0.f;
            #pragma unroll
            for (int k = 0; k < NCHUNK_; ++k)
                s += pooled_p[((size_t)k * N_ + n) * (T_ * C_) + i];
            pl[i] = s * (1.0f / 1024.0f);
        }
        for (int i = tid; i < C_ * R_; i += 256) {
            int r = i >> 7;
            int c = i & 127;
            twt[c * R_ + r] = tc_w[i];
        }
        __syncthreads();
        for (int o = tid; o < T_ * R_; o += 256) {
            int t = o >> 6;
            int r = o & 63;
            float acc = tc_b[r];
            #pragma unroll 4
            for (int c = 0; c < C_; ++c) acc += pl[t * C_ + c] * twt[c * R_ + r];
            TC[n * T_ * R_ + o] = sigm(acc);
        }
    } else {
        int c0 = (part - 33) * 32;
        float* pl = smem;              // [t][c] 1536
        float* sw = smem + 1536;       // [r][t] 768
        for (int i = tid; i < T_ * C_; i += 256) {
            float s = 0.f;
            #pragma unroll
            for (int k = 0; k < NCHUNK_; ++k)
                s += pooled_p[((size_t)k * N_ + n) * (T_ * C_) + i];
            pl[i] = s * (1.0f / 1024.0f);
        }
        for (int i = tid; i < R_ * T_; i += 256) sw[i] = sc_w[i];
        __syncthreads();
        for (int o = tid; o < 32 * R_; o += 256) {
            int c = c0 + (o >> 6);
            int r = o & 63;
            float acc = sc_b[r];
            #pragma unroll
            for (int t = 0; t < T_; ++t) acc += pl[t * C_ + c] * sw[r * T_ + t];
            SC[(size_t)n * C_ * R_ + c * R_ + r] = sigm(acc);
        }
    }
}

// K3: out[n,c,hw,t] = relu( (Σ_r TS[n,r,s]·TC[n,t,r]·SC[n,c,r]) * x[n,c,hw,t] )
// EXACT round-0 structure (measured 171 µs): thread = one (sl,t) column,
// w[64] from LDS-staged TS·TC, SC rows via wave-uniform scalar float4 loads,
// 4 accumulator chains, x loads grouped 4-wide.
// ONE change: c-loop split across blockIdx.z (64 channels per block) to double
// wave concurrency (4096 blocks × 3 waves = 48 waves/CU demanded).
__global__ __launch_bounds__(192) void k_main(const float* __restrict__ x,
                                              const float* __restrict__ TS,
                                              const float* __restrict__ TC,
                                              const float* __restrict__ SC,
                                              float* __restrict__ out) {
    int schunk = blockIdx.x;   // 0..63
    int n = blockIdx.y;
    int chalf = blockIdx.z;    // 0..1
    int tid = threadIdx.x;
    __shared__ float tst[R_ * 16];                // 4 KB
    __shared__ float tcl[T_ * R_];                // 3 KB
    int s0 = schunk * 16;
    for (int i = tid; i < R_ * 16; i += 192) {
        int r = i >> 4;
        int sl = i & 15;
        tst[i] = TS[(size_t)(n * R_ + r) * HW_ + s0 + sl];
    }
    for (int i = tid; i < T_ * R_; i += 192) tcl[i] = TC[n * T_ * R_ + i];
    __syncthreads();
    int sl = tid / T_;
    int t = tid - sl * T_;
    float w[R_];
    #pragma unroll
    for (int r = 0; r < R_; ++r) w[r] = tcl[t * R_ + r] * tst[r * 16 + sl];
    size_t base = (size_t)n * CHWT_ + (size_t)s0 * T_ + tid;
    const float* scb = SC + (size_t)n * C_ * R_;

    int cbeg = chalf * 64;
    int cend = cbeg + 64;
    for (int cg = cbeg; cg < cend; cg += 4) {
        float xg[4];
        #pragma unroll
        for (int cc = 0; cc < 4; ++cc)
            xg[cc] = x[base + (size_t)(cg + cc) * HWT_];
        #pragma unroll
        for (int cc = 0; cc < 4; ++cc) {
            const float4* sp = (const float4*)(scb + (size_t)(cg + cc) * R_);
            float a0 = 0.f, a1 = 0.f, a2 = 0.f, a3 = 0.f;
            #pragma unroll
            for (int r4 = 0; r4 < R_ / 4; ++r4) {
                float4 q = sp[r4];
                a0 = fmaf(q.x, w[4 * r4 + 0], a0);
                a1 = fmaf(q.y, w[4 * r4 + 1], a1);
                a2 = fmaf(q.z, w[4 * r4 + 2], a2);
                a3 = fmaf(q.w, w[4 * r4 + 3], a3);
            }
            float acc = (a0 + a1) + (a2 + a3);
            float rr = acc * xg[cc];
            size_t idx = base + (size_t)(cg + cc) * HWT_;
            out[idx] = rr > 0.f ? rr : 0.f;
        }
    }
}

extern "C" void kernel_launch(void* const* d_in, const int* in_sizes, int n_in,
                              void* d_out, int out_size, void* d_ws, size_t ws_size,
                              hipStream_t stream) {
    const float* x    = (const float*)d_in[0];
    const float* ts_w = (const float*)d_in[1];
    const float* ts_b = (const float*)d_in[2];
    const float* tc_w = (const float*)d_in[3];
    const float* tc_b = (const float*)d_in[4];
    const float* sc_w = (const float*)d_in[5];
    const float* sc_b = (const float*)d_in[6];
    float* out = (float*)d_out;

    float* ws       = (float*)d_ws;
    float* ts_in    = ws;                          // 393216 floats
    float* pooled_p = ts_in + 393216;              // 786432
    float* TS       = pooled_p + 786432;           // 2097152
    float* TC       = TS + 2097152;                // 24576
    float* SC       = TC + 24576;                  // 262144   (~14.3 MB)

    hipLaunchKernelGGL(k_stats, dim3(NCHUNK_, 32), dim3(256), 0, stream, x, ts_in, pooled_p);
    hipLaunchKernelGGL(k_mid, dim3(32, 37), dim3(256), 0, stream,
                       ts_in, ts_w, ts_b, pooled_p, tc_w, tc_b, sc_w, sc_b, TS, TC, SC);
    hipLaunchKernelGGL(k_main, dim3(64, 32, 2), dim3(192), 0, stream, x, TS, TC, SC, out);
}

// Round 5
// 469.947 us; speedup vs baseline: 5.4060x; 1.1437x over previous
//
#include <hip/hip_runtime.h>

#define N_ 32
#define C_ 128
#define H_ 32
#define W_ 32
#define T_ 12
#define R_ 64
#define HW_ (H_*W_)           // 1024
#define HWT_ (HW_*T_)         // 12288
#define CHWT_ ((size_t)C_*HW_*T_)  // 1572864
#define NCHUNK_ 16            // hw chunks of 64 for stats

__device__ __forceinline__ float sigm(float v) {
    return 1.0f / (1.0f + __expf(-v));
}

// K1: fused stats — ONE pass over x producing both
//   ts_in[n,t,hw] = mean_c x[n,c,hw,t]
//   pooled_p[chunk,n,t,c] = sum_{hw in chunk} x[n,c,hw,t]   (k_mid sums chunks)
__global__ __launch_bounds__(256) void k_stats(const float* __restrict__ x,
                                               float* __restrict__ ts_in,
                                               float* __restrict__ pooled_p) {
    int chunk = blockIdx.x;      // 0..15
    int n = blockIdx.y;
    int tid = threadIdx.x;
    int wave = tid >> 6;
    int lane = tid & 63;
    int hw = chunk * 64 + lane;

    __shared__ float ts_l[4][64 * T_];      // per-wave ts partials, 12 KB

    const float* xb = x + (size_t)n * CHWT_ + (size_t)hw * T_;

    float ts_acc[T_];
    #pragma unroll
    for (int j = 0; j < T_; ++j) ts_acc[j] = 0.f;

    int g = lane & 15;
    int up1 = g & 1, up2 = g & 2, up4 = g & 4, up8 = g & 8;
    int trev = ((g & 1) << 3) | ((g & 2) << 1) | ((g & 4) >> 1) | ((g & 8) >> 3);
    bool do_store = (lane < 16) && (trev < T_);
    float* pp = pooled_p + ((size_t)(chunk * N_ + n) * T_ + trev) * C_;

    #pragma unroll 2
    for (int ci = 0; ci < 32; ++ci) {
        int c = wave + 4 * ci;
        const float4* p = (const float4*)(xb + (size_t)c * HWT_);
        float4 v0 = p[0], v1 = p[1], v2 = p[2];
        float v[T_] = {v0.x, v0.y, v0.z, v0.w,
                       v1.x, v1.y, v1.z, v1.w,
                       v2.x, v2.y, v2.z, v2.w};
        #pragma unroll
        for (int j = 0; j < T_; ++j) ts_acc[j] += v[j];

        float wv[16];
        #pragma unroll
        for (int j = 0; j < T_; ++j) {
            float s = v[j];
            s += __shfl_xor(s, 32, 64);
            s += __shfl_xor(s, 16, 64);
            wv[j] = s;      // sum over lanes {l, l^16, l^32, l^48}
        }
        wv[12] = 0.f; wv[13] = 0.f; wv[14] = 0.f; wv[15] = 0.f;

        #pragma unroll
        for (int i = 0; i < 8; ++i) {
            float send = up1 ? wv[i] : wv[i + 8];
            float recv = __shfl_xor(send, 1, 64);
            wv[i] = (up1 ? wv[i + 8] : wv[i]) + recv;
        }
        #pragma unroll
        for (int i = 0; i < 4; ++i) {
            float send = up2 ? wv[i] : wv[i + 4];
            float recv = __shfl_xor(send, 2, 64);
            wv[i] = (up2 ? wv[i + 4] : wv[i]) + recv;
        }
        #pragma unroll
        for (int i = 0; i < 2; ++i) {
            float send = up4 ? wv[i] : wv[i + 2];
            float recv = __shfl_xor(send, 4, 64);
            wv[i] = (up4 ? wv[i + 2] : wv[i]) + recv;
        }
        {
            float send = up8 ? wv[0] : wv[1];
            float recv = __shfl_xor(send, 8, 64);
            wv[0] = (up8 ? wv[1] : wv[0]) + recv;
        }
        if (do_store) pp[c] = wv[0];   // raw partial; k_mid scales by 1/1024
    }

    #pragma unroll
    for (int j = 0; j < T_; ++j) ts_l[wave][lane * T_ + j] = ts_acc[j];
    __syncthreads();

    for (int i = tid; i < 64 * T_; i += 256) {
        float s = ts_l[0][i] + ts_l[1][i] + ts_l[2][i] + ts_l[3][i];
        int hwl = i / T_;
        int t = i - hwl * T_;
        ts_in[(n * T_ + t) * HW_ + chunk * 64 + hwl] = s * (1.0f / 128.0f);
    }
}

// K2: merged conv + linears. grid (n, 37): part<32 -> conv row h=part;
// part==32 -> TC; part 33..36 -> SC quarter.
__global__ __launch_bounds__(256) void k_mid(const float* __restrict__ ts_in,
                                             const float* __restrict__ ts_w,
                                             const float* __restrict__ ts_b,
                                             const float* __restrict__ pooled_p,
                                             const float* __restrict__ tc_w,
                                             const float* __restrict__ tc_b,
                                             const float* __restrict__ sc_w,
                                             const float* __restrict__ sc_b,
                                             float* __restrict__ TS,
                                             float* __restrict__ TC,
                                             float* __restrict__ SC) {
    int n = blockIdx.x;
    int part = blockIdx.y;
    int tid = threadIdx.x;
    __shared__ __align__(16) float smem[9728];

    if (part < 32) {
        int h = part;
        float* rows = smem;            // [3][12][36] padded rows, 1296
        float* wl = smem + 1296;       // 6912 weights
        for (int i = tid; i < 3 * T_ * 36; i += 256) {
            int kh = i / (T_ * 36);
            int rem = i - kh * (T_ * 36);
            int t = rem / 36;
            int wp = rem - t * 36;
            int hr = h + kh - 1;
            float v = 0.f;
            if (wp >= 1 && wp <= 32 && hr >= 0 && hr < H_)
                v = ts_in[((n * T_ + t) * H_ + hr) * W_ + (wp - 1)];
            rows[i] = v;
        }
        for (int i = tid; i < R_ * 108; i += 256) wl[i] = ts_w[i];
        __syncthreads();
        int r = tid >> 2;
        int j = tid & 3;      // 8 consecutive output w at j*8
        float acc[8];
        float b = ts_b[r];
        #pragma unroll
        for (int wi = 0; wi < 8; ++wi) acc[wi] = b;
        for (int t = 0; t < T_; ++t) {
            #pragma unroll
            for (int kh = 0; kh < 3; ++kh) {
                const float* rp = rows + (kh * T_ + t) * 36 + j * 8;
                float4 ra = *(const float4*)rp;
                float4 rb = *(const float4*)(rp + 4);
                float2 rc = *(const float2*)(rp + 8);
                float win[10] = {ra.x, ra.y, ra.z, ra.w,
                                 rb.x, rb.y, rb.z, rb.w, rc.x, rc.y};
                const float* wt = wl + r * 108 + t * 9 + kh * 3;
                float w0 = wt[0], w1 = wt[1], w2 = wt[2];
                #pragma unroll
                for (int wi = 0; wi < 8; ++wi)
                    acc[wi] += win[wi] * w0 + win[wi + 1] * w1 + win[wi + 2] * w2;
            }
        }
        float* outp = TS + (size_t)(n * R_ + r) * HW_ + h * W_ + j * 8;
        float4 o0 = {sigm(acc[0]), sigm(acc[1]), sigm(acc[2]), sigm(acc[3])};
        float4 o1 = {sigm(acc[4]), sigm(acc[5]), sigm(acc[6]), sigm(acc[7])};
        *(float4*)outp = o0;
        *(float4*)(outp + 4) = o1;
    } else if (part == 32) {
        float* pl = smem;              // [t][c] 1536
        float* twt = smem + 1536;      // [c][r] 8192
        for (int i = tid; i < T_ * C_; i += 256) {
            float s = 0.f;
            #pragma unroll
            for (int k = 0; k < NCHUNK_; ++k)
                s += pooled_p[((size_t)k * N_ + n) * (T_ * C_) + i];
            pl[i] = s * (1.0f / 1024.0f);
        }
        for (int i = tid; i < C_ * R_; i += 256) {
            int r = i >> 7;
            int c = i & 127;
            twt[c * R_ + r] = tc_w[i];
        }
        __syncthreads();
        for (int o = tid; o < T_ * R_; o += 256) {
            int t = o >> 6;
            int r = o & 63;
            float acc = tc_b[r];
            #pragma unroll 4
            for (int c = 0; c < C_; ++c) acc += pl[t * C_ + c] * twt[c * R_ + r];
            TC[n * T_ * R_ + o] = sigm(acc);
        }
    } else {
        int c0 = (part - 33) * 32;
        float* pl = smem;              // [t][c] 1536
        float* sw = smem + 1536;       // [r][t] 768
        for (int i = tid; i < T_ * C_; i += 256) {
            float s = 0.f;
            #pragma unroll
            for (int k = 0; k < NCHUNK_; ++k)
                s += pooled_p[((size_t)k * N_ + n) * (T_ * C_) + i];
            pl[i] = s * (1.0f / 1024.0f);
        }
        for (int i = tid; i < R_ * T_; i += 256) sw[i] = sc_w[i];
        __syncthreads();
        for (int o = tid; o < 32 * R_; o += 256) {
            int c = c0 + (o >> 6);
            int r = o & 63;
            float acc = sc_b[r];
            #pragma unroll
            for (int t = 0; t < T_; ++t) acc += pl[t * C_ + c] * sw[r * T_ + t];
            SC[(size_t)n * C_ * R_ + c * R_ + r] = sigm(acc);
        }
    }
}

// K3: register-tiled fp32 GEMM + fused x·relu.
// Per (n, s-chunk of 16): gate(128c × 192st) = SC(128×64) @ W(64×192),
// W[r][s*12+t] = TS[r,s0+s]·TC[t,r] built in LDS. K split into two 32-halves
// (LDS 47 KB -> 3 blocks/CU). Thread tile 8c × 12t: per k-step 5 ds_read_b128
// feed 96 FMAs (LDS:VALU = 60:192 cyc). Epilogue: dense float4 x loads,
// gate*x, relu, float4 stores.
__global__ __launch_bounds__(256, 2) void k_main(const float* __restrict__ x,
                                                 const float* __restrict__ TS,
                                                 const float* __restrict__ TC,
                                                 const float* __restrict__ SC,
                                                 float* __restrict__ out) {
    int schunk = blockIdx.x;   // 0..63
    int n = blockIdx.y;
    int tid = threadIdx.x;
    int s0 = schunk * 16;

    __shared__ __align__(16) float scT[32][128];   // 16 KB  [r-local][c]
    __shared__ __align__(16) float wls[32][192];   // 24 KB  [r-local][s*12+t]
    __shared__ float tss[R_ * 16];                 // 4 KB   TS[r][sl]
    __shared__ float tcs[T_ * R_];                 // 3 KB   TC[t][r]

    for (int i = tid; i < R_ * 16; i += 256)
        tss[i] = TS[(size_t)(n * R_ + (i >> 4)) * HW_ + s0 + (i & 15)];
    for (int i = tid; i < T_ * R_; i += 256)
        tcs[i] = TC[n * T_ * R_ + i];

    const float* scb = SC + (size_t)n * C_ * R_;
    int coct = tid >> 4;       // 0..15 -> c = coct*8 + i
    int sloc = tid & 15;       // 0..15 -> s = s0 + sloc

    float acc[8][12];
    #pragma unroll
    for (int ii = 0; ii < 8; ++ii)
        #pragma unroll
        for (int jj = 0; jj < 12; ++jj) acc[ii][jj] = 0.f;

    for (int kk = 0; kk < 2; ++kk) {
        int r0 = kk * 32;
        __syncthreads();   // tss/tcs ready (kk=0); prev-half reads done (kk=1)
        for (int i = tid; i < 32 * 128; i += 256) {
            int r = i >> 7, c = i & 127;
            scT[r][c] = scb[c * R_ + r0 + r];
        }
        for (int i = tid; i < 32 * 192; i += 256) {
            int r = i / 192;
            int st = i - r * 192;
            int s = st / 12;
            int t = st - s * 12;
            wls[r][st] = tss[(r0 + r) * 16 + s] * tcs[t * R_ + r0 + r];
        }
        __syncthreads();

        #pragma unroll 2
        for (int r = 0; r < 32; ++r) {
            float4 a0 = *(const float4*)&scT[r][coct * 8];
            float4 a1 = *(const float4*)&scT[r][coct * 8 + 4];
            float4 b0 = *(const float4*)&wls[r][sloc * 12];
            float4 b1 = *(const float4*)&wls[r][sloc * 12 + 4];
            float4 b2 = *(const float4*)&wls[r][sloc * 12 + 8];
            float av[8] = {a0.x, a0.y, a0.z, a0.w, a1.x, a1.y, a1.z, a1.w};
            float bv[12] = {b0.x, b0.y, b0.z, b0.w,
                            b1.x, b1.y, b1.z, b1.w,
                            b2.x, b2.y, b2.z, b2.w};
            #pragma unroll
            for (int ii = 0; ii < 8; ++ii)
                #pragma unroll
                for (int jj = 0; jj < 12; ++jj)
                    acc[ii][jj] = fmaf(av[ii], bv[jj], acc[ii][jj]);
        }
    }

    // epilogue: out = relu(gate * x), dense 48 B per (c, s)
    size_t sbase = (size_t)n * CHWT_ + (size_t)(s0 + sloc) * T_;
    #pragma unroll
    for (int ii = 0; ii < 8; ++ii) {
        int c = coct * 8 + ii;
        const float4* xp = (const float4*)(x + sbase + (size_t)c * HWT_);
        float4 x0 = xp[0], x1 = xp[1], x2 = xp[2];
        float4 o0, o1, o2;
        o0.x = acc[ii][0] * x0.x;  o0.y = acc[ii][1] * x0.y;
        o0.z = acc[ii][2] * x0.z;  o0.w = acc[ii][3] * x0.w;
        o1.x = acc[ii][4] * x1.x;  o1.y = acc[ii][5] * x1.y;
        o1.z = acc[ii][6] * x1.z;  o1.w = acc[ii][7] * x1.w;
        o2.x = acc[ii][8] * x2.x;  o2.y = acc[ii][9] * x2.y;
        o2.z = acc[ii][10] * x2.z; o2.w = acc[ii][11] * x2.w;
        o0.x = o0.x > 0.f ? o0.x : 0.f;  o0.y = o0.y > 0.f ? o0.y : 0.f;
        o0.z = o0.z > 0.f ? o0.z : 0.f;  o0.w = o0.w > 0.f ? o0.w : 0.f;
        o1.x = o1.x > 0.f ? o1.x : 0.f;  o1.y = o1.y > 0.f ? o1.y : 0.f;
        o1.z = o1.z > 0.f ? o1.z : 0.f;  o1.w = o1.w > 0.f ? o1.w : 0.f;
        o2.x = o2.x > 0.f ? o2.x : 0.f;  o2.y = o2.y > 0.f ? o2.y : 0.f;
        o2.z = o2.z > 0.f ? o2.z : 0.f;  o2.w = o2.w > 0.f ? o2.w : 0.f;
        float4* op = (float4*)(out + sbase + (size_t)c * HWT_);
        op[0] = o0; op[1] = o1; op[2] = o2;
    }
}

extern "C" void kernel_launch(void* const* d_in, const int* in_sizes, int n_in,
                              void* d_out, int out_size, void* d_ws, size_t ws_size,
                              hipStream_t stream) {
    const float* x    = (const float*)d_in[0];
    const float* ts_w = (const float*)d_in[1];
    const float* ts_b = (const float*)d_in[2];
    const float* tc_w = (const float*)d_in[3];
    const float* tc_b = (const float*)d_in[4];
    const float* sc_w = (const float*)d_in[5];
    const float* sc_b = (const float*)d_in[6];
    float* out = (float*)d_out;

    float* ws       = (float*)d_ws;
    float* ts_in    = ws;                          // 393216 floats
    float* pooled_p = ts_in + 393216;              // 786432
    float* TS       = pooled_p + 786432;           // 2097152
    float* TC       = TS + 2097152;                // 24576
    float* SC       = TC + 24576;                  // 262144   (~14.3 MB)

    hipLaunchKernelGGL(k_stats, dim3(NCHUNK_, 32), dim3(256), 0, stream, x, ts_in, pooled_p);
    hipLaunchKernelGGL(k_mid, dim3(32, 37), dim3(256), 0, stream,
                       ts_in, ts_w, ts_b, pooled_p, tc_w, tc_b, sc_w, sc_b, TS, TC, SC);
    hipLaunchKernelGGL(k_main, dim3(64, 32), dim3(256), 0, stream, x, TS, TC, SC, out);
}